// Round 7
// baseline (346.627 us; speedup 1.0000x reference)
//
#include <hip/hip_runtime.h>
#include <hip/hip_bf16.h>
#include <stdint.h>
#include <type_traits>

typedef unsigned short ushort_t;
typedef __bf16 bf16x8 __attribute__((ext_vector_type(8)));
typedef __bf16 bf16x4 __attribute__((ext_vector_type(4)));
typedef short s16x4 __attribute__((ext_vector_type(4)));
typedef unsigned short u16x8 __attribute__((ext_vector_type(8)));
typedef float f32x4 __attribute__((ext_vector_type(4)));

#define MFMA_BF16(a, b, c) __builtin_amdgcn_mfma_f32_16x16x32_bf16((a), (b), (c), 0, 0, 0)

#define GLD_LDS(gptr, lptr) \
    __builtin_amdgcn_global_load_lds((const __attribute__((address_space(1))) void*)(gptr), \
                                     (__attribute__((address_space(3))) void*)(lptr), 16, 0, 0)

static __device__ __forceinline__ float bf2f(__hip_bfloat16 x) { return __bfloat162float(x); }
static __device__ __forceinline__ ushort_t f2bfbits(float f) {
    __hip_bfloat16 h = __float2bfloat16(f);
    return *(ushort_t*)&h;
}
static __device__ __forceinline__ float fmax3(float a, float b, float c) {
    return fmaxf(fmaxf(a, b), c);  // clang fuses to v_max3_f32
}

// 16x16x16 bf16 MFMA with graceful fallback (zero-padded K=32 is exact).
static __device__ __forceinline__ f32x4 MFMA16(bf16x4 a, bf16x4 b, f32x4 c) {
#if __has_builtin(__builtin_amdgcn_mfma_f32_16x16x16_bf16)
    return __builtin_amdgcn_mfma_f32_16x16x16_bf16(a, b, c, 0, 0, 0);
#elif __has_builtin(__builtin_amdgcn_mfma_f32_16x16x16bf16_1k)
    union { bf16x4 b4; s16x4 s4; } ua, ub;
    ua.b4 = a; ub.b4 = b;
    return __builtin_amdgcn_mfma_f32_16x16x16bf16_1k(ua.s4, ub.s4, c, 0, 0, 0);
#else
    const bf16x4 z = {(__bf16)0.f, (__bf16)0.f, (__bf16)0.f, (__bf16)0.f};
    bf16x8 a8 = __builtin_shufflevector(a, z, 0, 1, 2, 3, 4, 5, 6, 7);
    bf16x8 b8 = __builtin_shufflevector(b, z, 0, 1, 2, 3, 4, 5, 6, 7);
    return MFMA_BF16(a8, b8, c);
#endif
}

static __device__ __forceinline__ bf16x4 pack4(float a, float b, float c, float d) {
    union { ushort4 u; bf16x4 v; } r;
    r.u = make_ushort4(f2bfbits(a), f2bfbits(b), f2bfbits(c), f2bfbits(d));
    return r.v;
}

template <typename T>
static __device__ __forceinline__ void storeT(T* p, float v);
template <>
__device__ __forceinline__ void storeT<float>(float* p, float v) { *p = v; }
template <>
__device__ __forceinline__ void storeT<__hip_bfloat16>(__hip_bfloat16* p, float v) {
    *p = __float2bfloat16(v);
}

// ---------------------------------------------------------------------------
// dtype probe + bias/slope pre-convert (tier-1 / fallback paths).
// ---------------------------------------------------------------------------
__global__ void detect_kernel(const ushort_t* __restrict__ X,
                              const void* bq, const void* bk, const void* bv,
                              const void* bo, const void* slopes,
                              int* flag, float* slopesF, float* bqF,
                              float* bkF, float* bvF, float* boF) {
    __shared__ int cnt_s;
    if (threadIdx.x == 0) cnt_s = 0;
    __syncthreads();
    int cnt = 0;
    for (int i = threadIdx.x; i < 8192; i += 256) {
        ushort_t u = X[2 * i];
        int ex = (u >> 7) & 0xFF;
        if (ex >= 0xC0) cnt++;
    }
    for (int off = 1; off < 64; off <<= 1) cnt += __shfl_xor(cnt, off);
    if ((threadIdx.x & 63) == 0) atomicAdd(&cnt_s, cnt);
    __syncthreads();
    const bool f32 = cnt_s > 100;
    if (threadIdx.x == 0) *flag = f32 ? 1 : 0;
    auto conv = [&](const void* src, float* dst, int n) {
        for (int i = threadIdx.x; i < n; i += 256)
            dst[i] = f32 ? ((const float*)src)[i]
                         : __bfloat162float(((const __hip_bfloat16*)src)[i]);
    };
    conv(bq, bqF, 2048);
    conv(bk, bkF, 512);
    conv(bv, bvF, 512);
    conv(bo, boF, 2048);
    conv(slopes, slopesF, 32);
}

// ---------------------------------------------------------------------------
// Bulk dtype convert (fp32->bf16 or bf16 copy).
// ---------------------------------------------------------------------------
__global__ __launch_bounds__(256) void cvt_kernel(const int* __restrict__ flag,
                                                  const void* __restrict__ src,
                                                  ushort_t* __restrict__ dst, int n4) {
    const bool f32 = (*flag == 1);
    const int stride = gridDim.x * 256;
    for (int i = blockIdx.x * 256 + threadIdx.x; i < n4; i += stride) {
        if (f32) {
            float4 f = ((const float4*)src)[i];
            ((ushort4*)dst)[i] =
                make_ushort4(f2bfbits(f.x), f2bfbits(f.y), f2bfbits(f.z), f2bfbits(f.w));
        } else {
            ((ushort4*)dst)[i] = ((const ushort4*)src)[i];
        }
    }
}

// ---------------------------------------------------------------------------
// Fused convert of X, Wq, Wk, Wv in ONE launch (tier-1).
// ---------------------------------------------------------------------------
__global__ __launch_bounds__(256) void cvt4_kernel(const int* __restrict__ flag,
                                                   const void* __restrict__ X,
                                                   const void* __restrict__ Wq,
                                                   const void* __restrict__ Wk,
                                                   const void* __restrict__ Wv,
                                                   ushort_t* __restrict__ Xb,
                                                   ushort_t* __restrict__ Wqb,
                                                   ushort_t* __restrict__ Wkb,
                                                   ushort_t* __restrict__ Wvb) {
    const bool f32 = (*flag == 1);
    constexpr int nX = 4096 * 2048 / 4;   // 2,097,152
    constexpr int nWq = 2048 * 2048 / 4;  // 1,048,576
    constexpr int nWk = 512 * 2048 / 4;   //   262,144
    constexpr int total = nX + nWq + 2 * nWk;
    const int stride = gridDim.x * 256;
    for (int i = blockIdx.x * 256 + threadIdx.x; i < total; i += stride) {
        const void* src;
        ushort_t* dst;
        int off;
        if (i < nX)                 { src = X;  dst = Xb;  off = i; }
        else if (i < nX + nWq)      { src = Wq; dst = Wqb; off = i - nX; }
        else if (i < nX + nWq + nWk){ src = Wk; dst = Wkb; off = i - nX - nWq; }
        else                        { src = Wv; dst = Wvb; off = i - nX - nWq - nWk; }
        if (f32) {
            float4 f = ((const float4*)src)[off];
            ((ushort4*)dst)[off] =
                make_ushort4(f2bfbits(f.x), f2bfbits(f.y), f2bfbits(f.z), f2bfbits(f.w));
        } else {
            ((ushort4*)dst)[off] = ((const ushort4*)src)[off];
        }
    }
}

// ---------------------------------------------------------------------------
// cvt5 (tier-2): ONE launch for X, Wq, Wk, Wv, Wo. Each block re-derives the
// f32 flag locally (deterministic scan of X's first 16KB, L2-hot after the
// first block); block 0 also converts biases/slopes. Removes the detect and
// Wo-cvt launches entirely -> 4-kernel pipeline.
// ---------------------------------------------------------------------------
__global__ __launch_bounds__(256) void cvt5_kernel(
    const void* __restrict__ X, const void* __restrict__ Wq,
    const void* __restrict__ Wk, const void* __restrict__ Wv,
    const void* __restrict__ Wo, const void* bq, const void* bk,
    const void* bv, const void* bo, const void* slopes,
    ushort_t* __restrict__ Xb, ushort_t* __restrict__ Wqb,
    ushort_t* __restrict__ Wkb, ushort_t* __restrict__ Wvb,
    ushort_t* __restrict__ Wob, float* slopesF, float* bqF,
    float* bkF, float* bvF, float* boF) {
    __shared__ int cnt_s;
    if (threadIdx.x == 0) cnt_s = 0;
    __syncthreads();
    int cnt = 0;
    const ushort_t* Xu = (const ushort_t*)X;
    for (int i = threadIdx.x; i < 8192; i += 256) {
        ushort_t u = Xu[2 * i];
        if (((u >> 7) & 0xFF) >= 0xC0) cnt++;
    }
    for (int off = 1; off < 64; off <<= 1) cnt += __shfl_xor(cnt, off);
    if ((threadIdx.x & 63) == 0) atomicAdd(&cnt_s, cnt);
    __syncthreads();
    const bool f32 = cnt_s > 100;

    if (blockIdx.x == 0) {
        auto conv = [&](const void* src, float* dst, int n) {
            for (int i = threadIdx.x; i < n; i += 256)
                dst[i] = f32 ? ((const float*)src)[i]
                             : __bfloat162float(((const __hip_bfloat16*)src)[i]);
        };
        conv(bq, bqF, 2048);
        conv(bk, bkF, 512);
        conv(bv, bvF, 512);
        conv(bo, boF, 2048);
        conv(slopes, slopesF, 32);
    }

    constexpr int nX = 4096 * 2048 / 4;
    constexpr int nWq = 2048 * 2048 / 4;
    constexpr int nWk = 512 * 2048 / 4;
    constexpr int total = nX + 2 * nWq + 2 * nWk;
    const int stride = gridDim.x * 256;
    for (int i = blockIdx.x * 256 + threadIdx.x; i < total; i += stride) {
        const void* src;
        ushort_t* dst;
        int off;
        if (i < nX)                        { src = X;  dst = Xb;  off = i; }
        else if (i < nX + nWq)             { src = Wq; dst = Wqb; off = i - nX; }
        else if (i < nX + nWq + nWk)       { src = Wk; dst = Wkb; off = i - nX - nWq; }
        else if (i < nX + nWq + 2 * nWk)   { src = Wv; dst = Wvb; off = i - nX - nWq - nWk; }
        else                               { src = Wo; dst = Wob; off = i - nX - nWq - 2 * nWk; }
        if (f32) {
            float4 f = ((const float4*)src)[off];
            ((ushort4*)dst)[off] =
                make_ushort4(f2bfbits(f.x), f2bfbits(f.y), f2bfbits(f.z), f2bfbits(f.w));
        } else {
            ((ushort4*)dst)[off] = ((const ushort4*)src)[off];
        }
    }
}

// ---------------------------------------------------------------------------
// GEMM tile staging into bf16 LDS [128][64] with XOR column-chunk swizzle.
// ---------------------------------------------------------------------------
__device__ __forceinline__ void stage_tile(const __hip_bfloat16* __restrict__ M, int K,
                                           int k0, ushort_t* lds, int tid) {
    const int wave = tid >> 6, lane = tid & 63;
    const int srow = lane >> 3;
    const int scol = ((lane & 7) ^ srow) * 8;
#pragma unroll
    for (int t = 0; t < 4; ++t) {
        const int chunk = wave * 4 + t;
        GLD_LDS((const ushort_t*)M + (size_t)(chunk * 8 + srow) * K + k0 + scol,
                lds + chunk * 512);
    }
}

__device__ __forceinline__ void stage_tile(const float* __restrict__ M, int K,
                                           int k0, ushort_t* lds, int tid) {
#pragma unroll
    for (int q = 0; q < 8; ++q) {
        const int idx = q * 256 + tid;
        const int row = idx >> 4;
        const int c4 = (idx & 15) * 4;
        float4 f = *(const float4*)(M + (size_t)row * K + k0 + c4);
        const int dcol = (((c4 >> 3) ^ (row & 7)) * 8) + (c4 & 7);
        *(ushort4*)(lds + row * 64 + dcol) =
            make_ushort4(f2bfbits(f.x), f2bfbits(f.y), f2bfbits(f.z), f2bfbits(f.w));
    }
}

// ---------------------------------------------------------------------------
// 128x128 GEMM tile, BK=128 (R6-proven: halves barrier-drain count, same
// occupancy at (256,2)). VTRANS=true writes the tile transposed as bf16
// ushort4 runs (V path: C[s][col] -> Vt[col_global][s], 4 consecutive s per
// lane = 8B stores, 32B contiguous per col group). Cv must point at
// Vt + (b*512 + colbase)*2048 + s_base.
// ---------------------------------------------------------------------------
template <bool VTRANS = false, typename TA, typename TW, typename TC>
__device__ __forceinline__ void gemm_tile(const TA* __restrict__ A,
                                          const TW* __restrict__ W,
                                          const float* __restrict__ biasF,
                                          TC* __restrict__ C, int K, int ldc) {
    __shared__ __align__(16) ushort_t As[2][128 * 64];
    __shared__ __align__(16) ushort_t Bs[2][128 * 64];
    const int tid = threadIdx.x;
    const int wave = tid >> 6, lane = tid & 63;
    const int quad = lane >> 4, l15 = lane & 15;
    const int wm = (wave >> 1) * 64, wn = (wave & 1) * 64;
    const int sw = l15 & 7;

    f32x4 acc[4][4];
#pragma unroll
    for (int i = 0; i < 4; ++i)
#pragma unroll
        for (int j = 0; j < 4; ++j) acc[i][j] = {0.f, 0.f, 0.f, 0.f};

    for (int k0 = 0; k0 < K; k0 += 128) {
        stage_tile(A, K, k0, As[0], tid);
        stage_tile(A, K, k0 + 64, As[1], tid);
        stage_tile(W, K, k0, Bs[0], tid);
        stage_tile(W, K, k0 + 64, Bs[1], tid);
        __syncthreads();
#pragma unroll
        for (int hh = 0; hh < 2; ++hh) {
            const ushort_t* Ab = As[hh];
            const ushort_t* Bb = Bs[hh];
#pragma unroll
            for (int kk = 0; kk < 2; ++kk) {
                const int chs = ((kk * 4 + quad) ^ sw) * 8;
                bf16x8 af[4], bfr[4];
#pragma unroll
                for (int mi = 0; mi < 4; ++mi)
                    af[mi] = *(const bf16x8*)(Ab + (wm + mi * 16 + l15) * 64 + chs);
#pragma unroll
                for (int ni = 0; ni < 4; ++ni)
                    bfr[ni] = *(const bf16x8*)(Bb + (wn + ni * 16 + l15) * 64 + chs);
#pragma unroll
                for (int mi = 0; mi < 4; ++mi)
#pragma unroll
                    for (int ni = 0; ni < 4; ++ni)
                        acc[mi][ni] = MFMA_BF16(af[mi], bfr[ni], acc[mi][ni]);
            }
        }
        __syncthreads();
    }
#pragma unroll
    for (int mi = 0; mi < 4; ++mi) {
#pragma unroll
        for (int ni = 0; ni < 4; ++ni) {
            const int col = wn + ni * 16 + l15;
            const float bv = biasF[col];
            if constexpr (VTRANS) {
                ushort4 o4 = make_ushort4(
                    f2bfbits(acc[mi][ni][0] + bv), f2bfbits(acc[mi][ni][1] + bv),
                    f2bfbits(acc[mi][ni][2] + bv), f2bfbits(acc[mi][ni][3] + bv));
                *(ushort4*)((ushort_t*)C + (size_t)col * 2048 + wm + mi * 16 + quad * 4) = o4;
            } else {
#pragma unroll
                for (int r = 0; r < 4; ++r) {
                    const int row = wm + mi * 16 + quad * 4 + r;
                    storeT(C + (size_t)row * ldc + col, acc[mi][ni][r] + bv);
                }
            }
        }
    }
}

// ======================== FAST PATH (pure-bf16 GEMMs) =======================
// V output (nt 20-23) is written DIRECTLY transposed into Vt — eliminates
// the separate vtrans kernel.
__global__ __launch_bounds__(256, 2) void qkv_fast(
    const __hip_bfloat16* __restrict__ X,
    const __hip_bfloat16* __restrict__ Wq, const __hip_bfloat16* __restrict__ Wk,
    const __hip_bfloat16* __restrict__ Wv, const float* __restrict__ bqF,
    const float* __restrict__ bkF, const float* __restrict__ bvF,
    __hip_bfloat16* __restrict__ Qb, __hip_bfloat16* __restrict__ Kb,
    ushort_t* __restrict__ Vt) {
    const int nt = blockIdx.x, mt = blockIdx.y;
    if (nt < 16) {
        const int colbase = nt * 128;
        gemm_tile(X + (size_t)mt * 128 * 2048, Wq + (size_t)colbase * 2048, bqF + colbase,
                  Qb + (size_t)mt * 128 * 2048 + colbase, 2048, 2048);
    } else if (nt < 20) {
        const int colbase = (nt - 16) * 128;
        gemm_tile(X + (size_t)mt * 128 * 2048, Wk + (size_t)colbase * 2048, bkF + colbase,
                  Kb + (size_t)mt * 128 * 512 + colbase, 2048, 512);
    } else {
        const int colbase = (nt - 20) * 128;
        // Vt[(b*512 + col)][s]: b = mt>>4, s_base = (mt&15)*128.
        ushort_t* Cv = Vt + ((size_t)((mt >> 4) * 512 + colbase)) * 2048 + (mt & 15) * 128;
        gemm_tile<true>(X + (size_t)mt * 128 * 2048, Wv + (size_t)colbase * 2048,
                        bvF + colbase, Cv, 2048, 0);
    }
}

__global__ __launch_bounds__(256, 2) void oproj_fast(
    const __hip_bfloat16* __restrict__ A, const __hip_bfloat16* __restrict__ Wo,
    const float* __restrict__ boF, float* __restrict__ C) {
    gemm_tile(A + (size_t)blockIdx.y * 128 * 2048,
              Wo + (size_t)blockIdx.x * 128 * 2048, boF + blockIdx.x * 128,
              C + (size_t)blockIdx.y * 128 * 2048 + blockIdx.x * 128, 2048, 2048);
}

// ==================== FALLBACK PATH GEMMs (round-3 style) ===================
template <bool F32>
__global__ __launch_bounds__(256, 2) void qkv_kernel(
    const int* __restrict__ flag, const void* __restrict__ Xv,
    const void* __restrict__ Wqv, const void* __restrict__ Wkv,
    const void* __restrict__ Wvv, const float* __restrict__ bqF,
    const float* __restrict__ bkF, const float* __restrict__ bvF,
    __hip_bfloat16* __restrict__ Qb, __hip_bfloat16* __restrict__ Kb,
    __hip_bfloat16* __restrict__ Vb) {
    if ((*flag == 1) != F32) return;
    using T = typename std::conditional<F32, float, __hip_bfloat16>::type;
    const T* X = (const T*)Xv;
    const int nt = blockIdx.x, mt = blockIdx.y;
    const T* W;
    const float* bias;
    __hip_bfloat16* C;
    int ldc, colbase;
    if (nt < 16)      { W = (const T*)Wqv; bias = bqF; C = Qb; ldc = 2048; colbase = nt * 128; }
    else if (nt < 20) { W = (const T*)Wkv; bias = bkF; C = Kb; ldc = 512;  colbase = (nt - 16) * 128; }
    else              { W = (const T*)Wvv; bias = bvF; C = Vb; ldc = 512;  colbase = (nt - 20) * 128; }
    gemm_tile(X + (size_t)mt * 128 * 2048, W + (size_t)colbase * 2048, bias + colbase,
              C + (size_t)mt * 128 * ldc + colbase, 2048, ldc);
}

template <bool F32>
__global__ __launch_bounds__(256, 2) void oproj_kernel(
    const int* __restrict__ flag, const __hip_bfloat16* __restrict__ A,
    const void* __restrict__ Wov, const float* __restrict__ boF,
    float* __restrict__ C) {
    if ((*flag == 1) != F32) return;
    using T = typename std::conditional<F32, float, __hip_bfloat16>::type;
    gemm_tile(A + (size_t)blockIdx.y * 128 * 2048,
              (const T*)Wov + (size_t)blockIdx.x * 128 * 2048, boF + blockIdx.x * 128,
              C + (size_t)blockIdx.y * 128 * 2048 + blockIdx.x * 128, 2048, 2048);
}

// ---------------------------------------------------------------------------
// Flash attention v5 (R2-proven structure; best measured 92.8-94.7us).
// R7 change: __launch_bounds__(256,4) -> (256,5). VGPR 60 << cap ~102;
// LDS 5x32KB = 160KB exactly -> resident blocks/CU 4 -> 5 for a
// latency-bound kernel at 28% time-avg occupancy.
// ---------------------------------------------------------------------------
__global__ __launch_bounds__(256, 5) void attn4_kernel(
    const __hip_bfloat16* __restrict__ Qg, const __hip_bfloat16* __restrict__ Kg,
    const ushort_t* __restrict__ Vt, const float* __restrict__ slopesF,
    __hip_bfloat16* __restrict__ Og) {
    constexpr int S = 2048, WIN = 1024;
    constexpr float LOG2E = 1.44269504f;
    constexpr float SCALE2 = 0.125f * LOG2E;
    constexpr float NEGBIG = -3e38f;
    __shared__ __align__(16) ushort_t K0s[64 * 64];
    __shared__ __align__(16) ushort_t V0s[64 * 64];
    __shared__ __align__(16) ushort_t K1s[64 * 64];
    __shared__ __align__(16) ushort_t V1s[64 * 64];

    // XCD-aware decode: blocks sharing (b,hkv) land on one XCD (p%8 = xcd).
    const int p = blockIdx.x;
    const int xcd = p & 7;
    const int slot = p >> 3;
    const int bh = (slot >> 7) * 8 + xcd;   // b*8 + hkv
    const int h2 = (slot >> 5) & 3;
    const int qt = 31 - (slot & 31);        // long blocks (high qt) first
    const int b = bh >> 3, hkv = bh & 7;
    const int h = hkv * 4 + h2;
    const int i0 = qt * 64;

    const int tid = threadIdx.x;
    const int wave = tid >> 6, lane = tid & 63;
    const int quad = lane >> 4, l15 = lane & 15;
    const int jl = lane >> 3, cc = lane & 7;
    const float slope2 = slopesF[h] * LOG2E;

    const ushort_t* kbase = (const ushort_t*)Kg + (size_t)(b * S) * 512 + hkv * 64;
    const ushort_t* vbase = Vt + ((size_t)bh * 64) * 2048;

    auto stage = [&](int j0, ushort_t* Ks, ushort_t* Vs) {
        const int row0 = wave * 16;
#pragma unroll
        for (int t = 0; t < 2; ++t) {
            const int r = row0 + t * 8 + jl;
            GLD_LDS(kbase + (size_t)(j0 + r) * 512 + ((cc ^ (r & 7)) * 8),
                    Ks + (row0 + t * 8) * 64);
            GLD_LDS(vbase + (size_t)r * 2048 + j0 + ((cc ^ (r & 7)) * 8),
                    Vs + (row0 + t * 8) * 64);
        }
    };

    // Q fragments: lane holds Q[row=i][dh=kk*32+quad*8+..] -> B-operand of K·Q^T
    const int i = i0 + wave * 16 + l15;  // this lane's q-row
    const __hip_bfloat16* qbase = Qg + ((size_t)(b * S + i)) * 2048 + h * 64;
    bf16x8 aq0 = *(const bf16x8*)(qbase + quad * 8);
    bf16x8 aq1 = *(const bf16x8*)(qbase + 32 + quad * 8);

    union { ushort4 u; bf16x4 v; } onesu;
    onesu.u = make_ushort4(0x3F80, 0x3F80, 0x3F80, 0x3F80);  // bf16 1.0 x4
    const bf16x4 onesf = onesu.v;

    f32x4 oaccT[4];  // O^T: lane holds q=i, dh = ni*16 + quad*4 + r
#pragma unroll
    for (int ni = 0; ni < 4; ++ni) oaccT[ni] = {0.f, 0.f, 0.f, 0.f};
    f32x4 lacc = {0.f, 0.f, 0.f, 0.f};  // lacc[0] = running sum of P for this q
    float m_i = -1e30f;

    auto compute = [&](int j0, const ushort_t* Ks, const ushort_t* Vs, bool masked) {
        // ---- S^T = K·Q^T : D[j=ni*16+quad*4+r][q=l15] ----
        f32x4 st[4];
#pragma unroll
        for (int ni = 0; ni < 4; ++ni) st[ni] = {0.f, 0.f, 0.f, 0.f};
#pragma unroll
        for (int kk = 0; kk < 2; ++kk) {
            const bf16x8 aqk = kk ? aq1 : aq0;
#pragma unroll
            for (int ni = 0; ni < 4; ++ni) {
                const int row = ni * 16 + l15;
                bf16x8 kf = *(const bf16x8*)(Ks + row * 64 + ((kk * 4 + quad) ^ (row & 7)) * 8);
                st[ni] = MFMA_BF16(kf, aqk, st[ni]);
            }
        }
        // ---- scores: all 16 j-values belong to THIS lane's q-row ----
        float sv[4][4];
#pragma unroll
        for (int ni = 0; ni < 4; ++ni)
#pragma unroll
            for (int r = 0; r < 4; ++r) {
                const int rel = (j0 + ni * 16 + quad * 4 + r) - i;
                sv[ni][r] = fmaf(st[ni][r], SCALE2, slope2 * (float)rel);
            }
        if (masked) {
#pragma unroll
            for (int ni = 0; ni < 4; ++ni)
#pragma unroll
                for (int r = 0; r < 4; ++r) {
                    const int rel = (j0 + ni * 16 + quad * 4 + r) - i;
                    if (!((unsigned)(-rel) < (unsigned)WIN)) sv[ni][r] = NEGBIG;
                }
        }
        // ---- row max: max3-shaped tree, then 2 cross-quad shuffles ----
        float mx = fmax3(fmax3(sv[0][0], sv[0][1], sv[0][2]),
                         fmax3(sv[0][3], sv[1][0], sv[1][1]),
                         fmax3(sv[1][2], sv[1][3], sv[2][0]));
        float my = fmax3(fmax3(sv[2][1], sv[2][2], sv[2][3]),
                         fmax3(sv[3][0], sv[3][1], sv[3][2]), sv[3][3]);
        mx = fmaxf(mx, my);
        mx = fmaxf(mx, __shfl_xor(mx, 16));
        mx = fmaxf(mx, __shfl_xor(mx, 32));
        // ---- defer-max: rescale only when the running max grew by > 8 ----
        if (!__all(mx <= m_i + 8.f)) {
            const float mn = fmaxf(m_i, mx);
            const float alpha = exp2f(m_i - mn);
            m_i = mn;
#pragma unroll
            for (int ni = 0; ni < 4; ++ni)
#pragma unroll
                for (int r = 0; r < 4; ++r) oaccT[ni][r] *= alpha;
            lacc[0] *= alpha;
        }
        float pv[4][4];
#pragma unroll
        for (int ni = 0; ni < 4; ++ni)
#pragma unroll
            for (int r = 0; r < 4; ++r) pv[ni][r] = exp2f(sv[ni][r] - m_i);
        // P fragments: B[k=quad*4+r][n=l15] for j-chunk c == register frag c. No LDS!
        bf16x4 pf[4];
#pragma unroll
        for (int c = 0; c < 4; ++c) pf[c] = pack4(pv[c][0], pv[c][1], pv[c][2], pv[c][3]);
        // row-sum via MFMA: D[m][q] = sum_k P[k][q] for every m -> lacc[0]
#pragma unroll
        for (int c = 0; c < 4; ++c) lacc = MFMA16(onesf, pf[c], lacc);
        // ---- O^T += V^T · P : A = V^T[dh=ni*16+l15][j=c*16+quad*4+..] (b64) ----
#pragma unroll
        for (int ni = 0; ni < 4; ++ni) {
            const int row = ni * 16 + l15;
#pragma unroll
            for (int c = 0; c < 4; ++c) {
                const int cj = c * 2 + (quad >> 1);
                bf16x4 vf = *(const bf16x4*)(Vs + row * 64 + ((cj ^ (row & 7)) * 8) +
                                             (quad & 1) * 4);
                oaccT[ni] = MFMA16(vf, pf[c], oaccT[ni]);
            }
        }
    };

    const int jt_lo = (i0 - WIN + 1) > 0 ? ((i0 - WIN + 1) >> 6) : 0;
    int jt = jt_lo;
    stage(jt * 64, K0s, V0s);
    for (;;) {
        __syncthreads();
        if (jt < qt) stage((jt + 1) * 64, K1s, V1s);
        compute(jt * 64, K0s, V0s, (jt == qt) || (qt - jt >= 16));
        if (++jt > qt) break;
        __syncthreads();
        if (jt < qt) stage((jt + 1) * 64, K0s, V0s);
        compute(jt * 64, K1s, V1s, (jt == qt) || (qt - jt >= 16));
        if (++jt > qt) break;
    }
    // epilogue: lane holds q=i; dh = ni*16+quad*4+r (consecutive r -> 8B stores)
    const float inv = 1.0f / lacc[0];
    __hip_bfloat16* obase = Og + ((size_t)(b * S + i)) * 2048 + h * 64;
#pragma unroll
    for (int ni = 0; ni < 4; ++ni) {
        ushort4 o4 = make_ushort4(f2bfbits(oaccT[ni][0] * inv), f2bfbits(oaccT[ni][1] * inv),
                                  f2bfbits(oaccT[ni][2] * inv), f2bfbits(oaccT[ni][3] * inv));
        *(ushort4*)((ushort_t*)obase + ni * 16 + quad * 4) = o4;
    }
}

// ---------------------------------------------------------------------------
// Fallback attention (round-3 proven; used when ws too small for fast path).
// ---------------------------------------------------------------------------
__global__ __launch_bounds__(256, 2) void attn_kernel(
    const __hip_bfloat16* __restrict__ Qg, const __hip_bfloat16* __restrict__ Kg,
    const __hip_bfloat16* __restrict__ Vg, const float* __restrict__ slopesF,
    __hip_bfloat16* __restrict__ Og) {
    constexpr int S = 2048, WIN = 1024;
    constexpr float SCALE = 0.125f;
    constexpr float LOG2E = 1.44269504f;
    __shared__ __align__(16) ushort_t P_lds[64 * 72];
    __shared__ __align__(16) ushort_t Vts[64 * 72];

    const int tile = blockIdx.x;
    const int qt = tile & 31;
    const int h = (tile >> 5) & 31;
    const int b = tile >> 10;
    const int i0 = qt * 64;
    const int hkv = h >> 2;
    const int tid = threadIdx.x;
    const int wave = tid >> 6, lane = tid & 63;
    const int quad = lane >> 4, l15 = lane & 15;
    const float slope = slopesF[h];

    const int qrow = i0 + wave * 16 + l15;
    const __hip_bfloat16* qbase = Qg + ((size_t)(b * S + qrow)) * 2048 + h * 64;
    bf16x8 aq[2];
    aq[0] = *(const bf16x8*)(qbase + quad * 8);
    aq[1] = *(const bf16x8*)(qbase + 32 + quad * 8);

    f32x4 oacc[4];
#pragma unroll
    for (int ni = 0; ni < 4; ++ni) oacc[ni] = {0.f, 0.f, 0.f, 0.f};
    float m_i[4], l_i[4];
#pragma unroll
    for (int r = 0; r < 4; ++r) { m_i[r] = -1e30f; l_i[r] = 0.f; }

    const int jt_lo = (i0 - WIN + 1) > 0 ? ((i0 - WIN + 1) >> 6) : 0;
    for (int jt = jt_lo; jt <= qt; ++jt) {
        const int j0 = jt * 64;
#pragma unroll
        for (int it = 0; it < 2; ++it) {
            const int j = it * 32 + (tid >> 3);
            const int dh0 = (tid & 7) * 8;
            u16x8 vv = *(const u16x8*)(Vg + ((size_t)(b * S + j0 + j)) * 512 + hkv * 64 + dh0);
#pragma unroll
            for (int e = 0; e < 8; ++e) Vts[(dh0 + e) * 72 + j] = vv[e];
        }
        f32x4 sacc[4];
#pragma unroll
        for (int ni = 0; ni < 4; ++ni) sacc[ni] = {0.f, 0.f, 0.f, 0.f};
#pragma unroll
        for (int kk = 0; kk < 2; ++kk) {
#pragma unroll
            for (int ni = 0; ni < 4; ++ni) {
                bf16x8 bkf = *(const bf16x8*)(Kg + ((size_t)(b * S + j0 + ni * 16 + l15)) * 512 +
                                              hkv * 64 + kk * 32 + quad * 8);
                sacc[ni] = MFMA_BF16(aq[kk], bkf, sacc[ni]);
            }
        }
#pragma unroll
        for (int r = 0; r < 4; ++r) {
            const int i = i0 + wave * 16 + quad * 4 + r;
            float sv[4];
            float rowmax = -1e30f;
#pragma unroll
            for (int ni = 0; ni < 4; ++ni) {
                const int j = j0 + ni * 16 + l15;
                float s = sacc[ni][r] * SCALE + slope * (float)(j - i);
                const bool valid = (j <= i) && ((i - j) < WIN);
                s = valid ? s : -1e30f;
                sv[ni] = s;
                rowmax = fmaxf(rowmax, s);
            }
#pragma unroll
            for (int off = 1; off < 16; off <<= 1)
                rowmax = fmaxf(rowmax, __shfl_xor(rowmax, off));
            const float mn = fmaxf(m_i[r], rowmax);
            const float alpha = exp2f((m_i[r] - mn) * LOG2E);
            float rowsum = 0.f;
#pragma unroll
            for (int ni = 0; ni < 4; ++ni) {
                const float p = (sv[ni] > -1e29f) ? exp2f((sv[ni] - mn) * LOG2E) : 0.f;
                P_lds[(wave * 16 + quad * 4 + r) * 72 + ni * 16 + l15] = f2bfbits(p);
                rowsum += p;
            }
#pragma unroll
            for (int off = 1; off < 16; off <<= 1) rowsum += __shfl_xor(rowsum, off);
            l_i[r] = l_i[r] * alpha + rowsum;
            m_i[r] = mn;
#pragma unroll
            for (int ni = 0; ni < 4; ++ni) oacc[ni][r] *= alpha;
        }
        __syncthreads();
#pragma unroll
        for (int kk = 0; kk < 2; ++kk) {
            bf16x8 ap = *(const bf16x8*)(P_lds + (wave * 16 + l15) * 72 + kk * 32 + quad * 8);
#pragma unroll
            for (int ni = 0; ni < 4; ++ni) {
                bf16x8 bvf = *(const bf16x8*)(Vts + (ni * 16 + l15) * 72 + kk * 32 + quad * 8);
                oacc[ni] = MFMA_BF16(ap, bvf, oacc[ni]);
            }
        }
        __syncthreads();
    }
#pragma unroll
    for (int ni = 0; ni < 4; ++ni) {
#pragma unroll
        for (int r = 0; r < 4; ++r) {
            const int srow = i0 + wave * 16 + quad * 4 + r;
            const float v = oacc[ni][r] / l_i[r];
            Og[((size_t)(b * S + srow)) * 2048 + h * 64 + ni * 16 + l15] = __float2bfloat16(v);
        }
    }
}

extern "C" void kernel_launch(void* const* d_in, const int* in_sizes, int n_in,
                              void* d_out, int out_size, void* d_ws, size_t ws_size,
                              hipStream_t stream) {
    (void)in_sizes; (void)n_in; (void)out_size;
    const void* X  = d_in[0];
    const void* Wq = d_in[1];
    const void* bq = d_in[2];
    const void* Wk = d_in[3];
    const void* bk = d_in[4];
    const void* Wv = d_in[5];
    const void* bv = d_in[6];
    const void* Wo = d_in[7];
    const void* bo = d_in[8];
    const void* sl = d_in[9];
    float* outp = (float*)d_out;

    char* ws = (char*)d_ws;
    const size_t SZ_X  = (size_t)4096 * 2048 * 2;
    const size_t SZ_WQ = (size_t)2048 * 2048 * 2;
    const size_t SZ_WK = (size_t)512 * 2048 * 2;
    const size_t SZ_Q  = SZ_X;
    const size_t SZ_K  = (size_t)4096 * 512 * 2;
    const size_t FAST_NEED  = SZ_X + SZ_WQ + 2 * SZ_WK + SZ_Q + 2 * SZ_K + 65536;
    const size_t FAST_NEED2 = FAST_NEED + SZ_WQ;  // + separate Wob

    if (ws_size >= FAST_NEED) {
        size_t o = 0;
        __hip_bfloat16* Xb  = (__hip_bfloat16*)(ws + o); o += SZ_X;
        __hip_bfloat16* Wqb = (__hip_bfloat16*)(ws + o); o += SZ_WQ;
        __hip_bfloat16* Wkb = (__hip_bfloat16*)(ws + o); o += SZ_WK;
        __hip_bfloat16* Wvb = (__hip_bfloat16*)(ws + o); o += SZ_WK;
        __hip_bfloat16* Qb  = (__hip_bfloat16*)(ws + o); o += SZ_Q;
        __hip_bfloat16* Kb  = (__hip_bfloat16*)(ws + o); o += SZ_K;
        ushort_t*       Vtg = (ushort_t*)(ws + o);       o += SZ_K;  // Vt lives in Vb slot
        __hip_bfloat16* Ab  = Xb;             // X dead after qkv_fast
        int*   flag    = (int*)(ws + o);
        float* slopesF = (float*)(ws + o + 1024);
        float* bqF     = (float*)(ws + o + 4096);
        float* bkF     = bqF + 2048;
        float* bvF     = bkF + 512;
        float* boF     = bvF + 512;

        if (ws_size >= FAST_NEED2) {
            // ---- tier-2: 4-kernel pipeline, separate Wob ----
            __hip_bfloat16* Wob = (__hip_bfloat16*)(ws + o + 65536);
            cvt5_kernel<<<2048, 256, 0, stream>>>(
                X, Wq, Wk, Wv, Wo, bq, bk, bv, bo, sl, (ushort_t*)Xb, (ushort_t*)Wqb,
                (ushort_t*)Wkb, (ushort_t*)Wvb, (ushort_t*)Wob, slopesF, bqF, bkF, bvF,
                boF);
            qkv_fast<<<dim3(24, 32), 256, 0, stream>>>(Xb, Wqb, Wkb, Wvb, bqF, bkF, bvF,
                                                       Qb, Kb, Vtg);
            attn4_kernel<<<dim3(2048), 256, 0, stream>>>(Qb, Kb, Vtg, slopesF, Ab);
            oproj_fast<<<dim3(16, 32), 256, 0, stream>>>(Ab, Wob, boF, outp);
        } else {
            // ---- tier-1: Wob aliases Wqb (cvt after qkv) ----
            __hip_bfloat16* Wob = Wqb;
            detect_kernel<<<1, 256, 0, stream>>>((const ushort_t*)X, bq, bk, bv, bo, sl,
                                                 flag, slopesF, bqF, bkF, bvF, boF);
            cvt4_kernel<<<2048, 256, 0, stream>>>(flag, X, Wq, Wk, Wv, (ushort_t*)Xb,
                                                  (ushort_t*)Wqb, (ushort_t*)Wkb,
                                                  (ushort_t*)Wvb);
            qkv_fast<<<dim3(24, 32), 256, 0, stream>>>(Xb, Wqb, Wkb, Wvb, bqF, bkF, bvF,
                                                       Qb, Kb, Vtg);
            cvt_kernel<<<2048, 256, 0, stream>>>(flag, Wo, (ushort_t*)Wob, 2048 * 2048 / 4);
            attn4_kernel<<<dim3(2048), 256, 0, stream>>>(Qb, Kb, Vtg, slopesF, Ab);
            oproj_fast<<<dim3(16, 32), 256, 0, stream>>>(Ab, Wob, boF, outp);
        }
    } else {
        const size_t MB = 1024 * 1024;
        __hip_bfloat16* Qb = (__hip_bfloat16*)(ws);
        __hip_bfloat16* Kb = (__hip_bfloat16*)(ws + 16 * MB);
        __hip_bfloat16* Vb = (__hip_bfloat16*)(ws + 20 * MB);
        __hip_bfloat16* Ab = (__hip_bfloat16*)(ws + 24 * MB);
        int*   flag    = (int*)(ws + 40 * MB);
        float* slopesF = (float*)(ws + 40 * MB + 1024);
        float* bqF     = (float*)(ws + 40 * MB + 4096);
        float* bkF     = bqF + 2048;
        float* bvF     = bkF + 512;
        float* boF     = bvF + 512;

        detect_kernel<<<1, 256, 0, stream>>>((const ushort_t*)X, bq, bk, bv, bo, sl,
                                             flag, slopesF, bqF, bkF, bvF, boF);
        qkv_kernel<false><<<dim3(24, 32), 256, 0, stream>>>(flag, X, Wq, Wk, Wv,
                                                            bqF, bkF, bvF, Qb, Kb, Vb);
        qkv_kernel<true><<<dim3(24, 32), 256, 0, stream>>>(flag, X, Wq, Wk, Wv,
                                                           bqF, bkF, bvF, Qb, Kb, Vb);
        attn_kernel<<<dim3(2048), 256, 0, stream>>>(Qb, Kb, Vb, slopesF, Ab);
        oproj_kernel<false><<<dim3(16, 32), 256, 0, stream>>>(flag, Ab, Wo, boF, outp);
        oproj_kernel<true><<<dim3(16, 32), 256, 0, stream>>>(flag, Ab, Wo, boF, outp);
    }
}

// Round 8
// 316.829 us; speedup vs baseline: 1.0941x; 1.0941x over previous
//
#include <hip/hip_runtime.h>
#include <hip/hip_bf16.h>
#include <stdint.h>
#include <type_traits>

typedef unsigned short ushort_t;
typedef __bf16 bf16x8 __attribute__((ext_vector_type(8)));
typedef __bf16 bf16x4 __attribute__((ext_vector_type(4)));
typedef short s16x4 __attribute__((ext_vector_type(4)));
typedef unsigned short u16x8 __attribute__((ext_vector_type(8)));
typedef float f32x4 __attribute__((ext_vector_type(4)));

#define MFMA_BF16(a, b, c) __builtin_amdgcn_mfma_f32_16x16x32_bf16((a), (b), (c), 0, 0, 0)

#define GLD_LDS(gptr, lptr) \
    __builtin_amdgcn_global_load_lds((const __attribute__((address_space(1))) void*)(gptr), \
                                     (__attribute__((address_space(3))) void*)(lptr), 16, 0, 0)

static __device__ __forceinline__ float bf2f(__hip_bfloat16 x) { return __bfloat162float(x); }
static __device__ __forceinline__ ushort_t f2bfbits(float f) {
    __hip_bfloat16 h = __float2bfloat16(f);
    return *(ushort_t*)&h;
}
static __device__ __forceinline__ float fmax3(float a, float b, float c) {
    return fmaxf(fmaxf(a, b), c);  // clang fuses to v_max3_f32
}

// 16x16x16 bf16 MFMA with graceful fallback (zero-padded K=32 is exact).
static __device__ __forceinline__ f32x4 MFMA16(bf16x4 a, bf16x4 b, f32x4 c) {
#if __has_builtin(__builtin_amdgcn_mfma_f32_16x16x16_bf16)
    return __builtin_amdgcn_mfma_f32_16x16x16_bf16(a, b, c, 0, 0, 0);
#elif __has_builtin(__builtin_amdgcn_mfma_f32_16x16x16bf16_1k)
    union { bf16x4 b4; s16x4 s4; } ua, ub;
    ua.b4 = a; ub.b4 = b;
    return __builtin_amdgcn_mfma_f32_16x16x16bf16_1k(ua.s4, ub.s4, c, 0, 0, 0);
#else
    const bf16x4 z = {(__bf16)0.f, (__bf16)0.f, (__bf16)0.f, (__bf16)0.f};
    bf16x8 a8 = __builtin_shufflevector(a, z, 0, 1, 2, 3, 4, 5, 6, 7);
    bf16x8 b8 = __builtin_shufflevector(b, z, 0, 1, 2, 3, 4, 5, 6, 7);
    return MFMA_BF16(a8, b8, c);
#endif
}

static __device__ __forceinline__ bf16x4 pack4(float a, float b, float c, float d) {
    union { ushort4 u; bf16x4 v; } r;
    r.u = make_ushort4(f2bfbits(a), f2bfbits(b), f2bfbits(c), f2bfbits(d));
    return r.v;
}

template <typename T>
static __device__ __forceinline__ void storeT(T* p, float v);
template <>
__device__ __forceinline__ void storeT<float>(float* p, float v) { *p = v; }
template <>
__device__ __forceinline__ void storeT<__hip_bfloat16>(__hip_bfloat16* p, float v) {
    *p = __float2bfloat16(v);
}

// ---------------------------------------------------------------------------
// dtype probe + bias/slope pre-convert (tier-1 / fallback paths).
// ---------------------------------------------------------------------------
__global__ void detect_kernel(const ushort_t* __restrict__ X,
                              const void* bq, const void* bk, const void* bv,
                              const void* bo, const void* slopes,
                              int* flag, float* slopesF, float* bqF,
                              float* bkF, float* bvF, float* boF) {
    __shared__ int cnt_s;
    if (threadIdx.x == 0) cnt_s = 0;
    __syncthreads();
    int cnt = 0;
    for (int i = threadIdx.x; i < 8192; i += 256) {
        ushort_t u = X[2 * i];
        int ex = (u >> 7) & 0xFF;
        if (ex >= 0xC0) cnt++;
    }
    for (int off = 1; off < 64; off <<= 1) cnt += __shfl_xor(cnt, off);
    if ((threadIdx.x & 63) == 0) atomicAdd(&cnt_s, cnt);
    __syncthreads();
    const bool f32 = cnt_s > 100;
    if (threadIdx.x == 0) *flag = f32 ? 1 : 0;
    auto conv = [&](const void* src, float* dst, int n) {
        for (int i = threadIdx.x; i < n; i += 256)
            dst[i] = f32 ? ((const float*)src)[i]
                         : __bfloat162float(((const __hip_bfloat16*)src)[i]);
    };
    conv(bq, bqF, 2048);
    conv(bk, bkF, 512);
    conv(bv, bvF, 512);
    conv(bo, boF, 2048);
    conv(slopes, slopesF, 32);
}

// ---------------------------------------------------------------------------
// Bulk dtype convert (fp32->bf16 or bf16 copy).
// ---------------------------------------------------------------------------
__global__ __launch_bounds__(256) void cvt_kernel(const int* __restrict__ flag,
                                                  const void* __restrict__ src,
                                                  ushort_t* __restrict__ dst, int n4) {
    const bool f32 = (*flag == 1);
    const int stride = gridDim.x * 256;
    for (int i = blockIdx.x * 256 + threadIdx.x; i < n4; i += stride) {
        if (f32) {
            float4 f = ((const float4*)src)[i];
            ((ushort4*)dst)[i] =
                make_ushort4(f2bfbits(f.x), f2bfbits(f.y), f2bfbits(f.z), f2bfbits(f.w));
        } else {
            ((ushort4*)dst)[i] = ((const ushort4*)src)[i];
        }
    }
}

// ---------------------------------------------------------------------------
// Fused convert of X, Wq, Wk, Wv in ONE launch (tier-1).
// ---------------------------------------------------------------------------
__global__ __launch_bounds__(256) void cvt4_kernel(const int* __restrict__ flag,
                                                   const void* __restrict__ X,
                                                   const void* __restrict__ Wq,
                                                   const void* __restrict__ Wk,
                                                   const void* __restrict__ Wv,
                                                   ushort_t* __restrict__ Xb,
                                                   ushort_t* __restrict__ Wqb,
                                                   ushort_t* __restrict__ Wkb,
                                                   ushort_t* __restrict__ Wvb) {
    const bool f32 = (*flag == 1);
    constexpr int nX = 4096 * 2048 / 4;   // 2,097,152
    constexpr int nWq = 2048 * 2048 / 4;  // 1,048,576
    constexpr int nWk = 512 * 2048 / 4;   //   262,144
    constexpr int total = nX + nWq + 2 * nWk;
    const int stride = gridDim.x * 256;
    for (int i = blockIdx.x * 256 + threadIdx.x; i < total; i += stride) {
        const void* src;
        ushort_t* dst;
        int off;
        if (i < nX)                 { src = X;  dst = Xb;  off = i; }
        else if (i < nX + nWq)      { src = Wq; dst = Wqb; off = i - nX; }
        else if (i < nX + nWq + nWk){ src = Wk; dst = Wkb; off = i - nX - nWq; }
        else                        { src = Wv; dst = Wvb; off = i - nX - nWq - nWk; }
        if (f32) {
            float4 f = ((const float4*)src)[off];
            ((ushort4*)dst)[off] =
                make_ushort4(f2bfbits(f.x), f2bfbits(f.y), f2bfbits(f.z), f2bfbits(f.w));
        } else {
            ((ushort4*)dst)[off] = ((const ushort4*)src)[off];
        }
    }
}

// ---------------------------------------------------------------------------
// cvt5 (tier-2): ONE launch for X, Wq, Wk, Wv, Wo. Each block re-derives the
// f32 flag locally; block 0 also converts biases/slopes.
// ---------------------------------------------------------------------------
__global__ __launch_bounds__(256) void cvt5_kernel(
    const void* __restrict__ X, const void* __restrict__ Wq,
    const void* __restrict__ Wk, const void* __restrict__ Wv,
    const void* __restrict__ Wo, const void* bq, const void* bk,
    const void* bv, const void* bo, const void* slopes,
    ushort_t* __restrict__ Xb, ushort_t* __restrict__ Wqb,
    ushort_t* __restrict__ Wkb, ushort_t* __restrict__ Wvb,
    ushort_t* __restrict__ Wob, float* slopesF, float* bqF,
    float* bkF, float* bvF, float* boF) {
    __shared__ int cnt_s;
    if (threadIdx.x == 0) cnt_s = 0;
    __syncthreads();
    int cnt = 0;
    const ushort_t* Xu = (const ushort_t*)X;
    for (int i = threadIdx.x; i < 8192; i += 256) {
        ushort_t u = Xu[2 * i];
        if (((u >> 7) & 0xFF) >= 0xC0) cnt++;
    }
    for (int off = 1; off < 64; off <<= 1) cnt += __shfl_xor(cnt, off);
    if ((threadIdx.x & 63) == 0) atomicAdd(&cnt_s, cnt);
    __syncthreads();
    const bool f32 = cnt_s > 100;

    if (blockIdx.x == 0) {
        auto conv = [&](const void* src, float* dst, int n) {
            for (int i = threadIdx.x; i < n; i += 256)
                dst[i] = f32 ? ((const float*)src)[i]
                             : __bfloat162float(((const __hip_bfloat16*)src)[i]);
        };
        conv(bq, bqF, 2048);
        conv(bk, bkF, 512);
        conv(bv, bvF, 512);
        conv(bo, boF, 2048);
        conv(slopes, slopesF, 32);
    }

    constexpr int nX = 4096 * 2048 / 4;
    constexpr int nWq = 2048 * 2048 / 4;
    constexpr int nWk = 512 * 2048 / 4;
    constexpr int total = nX + 2 * nWq + 2 * nWk;
    const int stride = gridDim.x * 256;
    for (int i = blockIdx.x * 256 + threadIdx.x; i < total; i += stride) {
        const void* src;
        ushort_t* dst;
        int off;
        if (i < nX)                        { src = X;  dst = Xb;  off = i; }
        else if (i < nX + nWq)             { src = Wq; dst = Wqb; off = i - nX; }
        else if (i < nX + nWq + nWk)       { src = Wk; dst = Wkb; off = i - nX - nWq; }
        else if (i < nX + nWq + 2 * nWk)   { src = Wv; dst = Wvb; off = i - nX - nWq - nWk; }
        else                               { src = Wo; dst = Wob; off = i - nX - nWq - 2 * nWk; }
        if (f32) {
            float4 f = ((const float4*)src)[off];
            ((ushort4*)dst)[off] =
                make_ushort4(f2bfbits(f.x), f2bfbits(f.y), f2bfbits(f.z), f2bfbits(f.w));
        } else {
            ((ushort4*)dst)[off] = ((const ushort4*)src)[off];
        }
    }
}

// ---------------------------------------------------------------------------
// GEMM tile staging into bf16 LDS [128][64] with XOR column-chunk swizzle.
// ---------------------------------------------------------------------------
__device__ __forceinline__ void stage_tile(const __hip_bfloat16* __restrict__ M, int K,
                                           int k0, ushort_t* lds, int tid) {
    const int wave = tid >> 6, lane = tid & 63;
    const int srow = lane >> 3;
    const int scol = ((lane & 7) ^ srow) * 8;
#pragma unroll
    for (int t = 0; t < 4; ++t) {
        const int chunk = wave * 4 + t;
        GLD_LDS((const ushort_t*)M + (size_t)(chunk * 8 + srow) * K + k0 + scol,
                lds + chunk * 512);
    }
}

__device__ __forceinline__ void stage_tile(const float* __restrict__ M, int K,
                                           int k0, ushort_t* lds, int tid) {
#pragma unroll
    for (int q = 0; q < 8; ++q) {
        const int idx = q * 256 + tid;
        const int row = idx >> 4;
        const int c4 = (idx & 15) * 4;
        float4 f = *(const float4*)(M + (size_t)row * K + k0 + c4);
        const int dcol = (((c4 >> 3) ^ (row & 7)) * 8) + (c4 & 7);
        *(ushort4*)(lds + row * 64 + dcol) =
            make_ushort4(f2bfbits(f.x), f2bfbits(f.y), f2bfbits(f.z), f2bfbits(f.w));
    }
}

// ---------------------------------------------------------------------------
// 128x128 GEMM tile, BK=128 (R6-proven). The V-transpose epilogue is a
// RUNTIME (block-uniform) flag, NOT a template parameter: R7's template split
// created two inlined instantiations each with its own static __shared__
// arrays -> 128KB LDS -> 1 block/CU (measured: LDS_Block_Size=131072,
// occupancy 10.5%). One instantiation = 64KB = 2 blocks/CU.
// vtrans=true (2-byte TC only): C[s][col] -> Ct[col_global*2048 + s],
// 4 consecutive s per lane = 8B stores.
// ---------------------------------------------------------------------------
template <typename TA, typename TW, typename TC>
__device__ __forceinline__ void gemm_tile(const TA* __restrict__ A,
                                          const TW* __restrict__ W,
                                          const float* __restrict__ biasF,
                                          TC* __restrict__ C, int K, int ldc,
                                          bool vtrans = false) {
    __shared__ __align__(16) ushort_t As[2][128 * 64];
    __shared__ __align__(16) ushort_t Bs[2][128 * 64];
    const int tid = threadIdx.x;
    const int wave = tid >> 6, lane = tid & 63;
    const int quad = lane >> 4, l15 = lane & 15;
    const int wm = (wave >> 1) * 64, wn = (wave & 1) * 64;
    const int sw = l15 & 7;

    f32x4 acc[4][4];
#pragma unroll
    for (int i = 0; i < 4; ++i)
#pragma unroll
        for (int j = 0; j < 4; ++j) acc[i][j] = {0.f, 0.f, 0.f, 0.f};

    for (int k0 = 0; k0 < K; k0 += 128) {
        stage_tile(A, K, k0, As[0], tid);
        stage_tile(A, K, k0 + 64, As[1], tid);
        stage_tile(W, K, k0, Bs[0], tid);
        stage_tile(W, K, k0 + 64, Bs[1], tid);
        __syncthreads();
#pragma unroll
        for (int hh = 0; hh < 2; ++hh) {
            const ushort_t* Ab = As[hh];
            const ushort_t* Bb = Bs[hh];
#pragma unroll
            for (int kk = 0; kk < 2; ++kk) {
                const int chs = ((kk * 4 + quad) ^ sw) * 8;
                bf16x8 af[4], bfr[4];
#pragma unroll
                for (int mi = 0; mi < 4; ++mi)
                    af[mi] = *(const bf16x8*)(Ab + (wm + mi * 16 + l15) * 64 + chs);
#pragma unroll
                for (int ni = 0; ni < 4; ++ni)
                    bfr[ni] = *(const bf16x8*)(Bb + (wn + ni * 16 + l15) * 64 + chs);
#pragma unroll
                for (int mi = 0; mi < 4; ++mi)
#pragma unroll
                    for (int ni = 0; ni < 4; ++ni)
                        acc[mi][ni] = MFMA_BF16(af[mi], bfr[ni], acc[mi][ni]);
            }
        }
        __syncthreads();
    }
    if constexpr (sizeof(TC) == 2) {
        if (vtrans) {
#pragma unroll
            for (int mi = 0; mi < 4; ++mi) {
#pragma unroll
                for (int ni = 0; ni < 4; ++ni) {
                    const int col = wn + ni * 16 + l15;
                    const float bv = biasF[col];
                    ushort4 o4 = make_ushort4(
                        f2bfbits(acc[mi][ni][0] + bv), f2bfbits(acc[mi][ni][1] + bv),
                        f2bfbits(acc[mi][ni][2] + bv), f2bfbits(acc[mi][ni][3] + bv));
                    *(ushort4*)((ushort_t*)C + (size_t)col * 2048 + wm + mi * 16 +
                                quad * 4) = o4;
                }
            }
            return;
        }
    }
#pragma unroll
    for (int mi = 0; mi < 4; ++mi) {
#pragma unroll
        for (int ni = 0; ni < 4; ++ni) {
            const int col = wn + ni * 16 + l15;
            const float bv = biasF[col];
#pragma unroll
            for (int r = 0; r < 4; ++r) {
                const int row = wm + mi * 16 + quad * 4 + r;
                storeT(C + (size_t)row * ldc + col, acc[mi][ni][r] + bv);
            }
        }
    }
}

// ======================== FAST PATH (pure-bf16 GEMMs) =======================
// V output (nt 20-23) is written DIRECTLY transposed into Vt (runtime flag,
// single gemm_tile instantiation -> 64KB LDS, 2 blocks/CU).
__global__ __launch_bounds__(256, 2) void qkv_fast(
    const __hip_bfloat16* __restrict__ X,
    const __hip_bfloat16* __restrict__ Wq, const __hip_bfloat16* __restrict__ Wk,
    const __hip_bfloat16* __restrict__ Wv, const float* __restrict__ bqF,
    const float* __restrict__ bkF, const float* __restrict__ bvF,
    __hip_bfloat16* __restrict__ Qb, __hip_bfloat16* __restrict__ Kb,
    ushort_t* __restrict__ Vt) {
    const int nt = blockIdx.x, mt = blockIdx.y;
    if (nt < 16) {
        const int colbase = nt * 128;
        gemm_tile(X + (size_t)mt * 128 * 2048, Wq + (size_t)colbase * 2048, bqF + colbase,
                  Qb + (size_t)mt * 128 * 2048 + colbase, 2048, 2048, false);
    } else if (nt < 20) {
        const int colbase = (nt - 16) * 128;
        gemm_tile(X + (size_t)mt * 128 * 2048, Wk + (size_t)colbase * 2048, bkF + colbase,
                  Kb + (size_t)mt * 128 * 512 + colbase, 2048, 512, false);
    } else {
        const int colbase = (nt - 20) * 128;
        // Vt[(b*512 + col)][s]: b = mt>>4, s_base = (mt&15)*128.
        __hip_bfloat16* Cv = (__hip_bfloat16*)(Vt +
            ((size_t)((mt >> 4) * 512 + colbase)) * 2048 + (mt & 15) * 128);
        gemm_tile(X + (size_t)mt * 128 * 2048, Wv + (size_t)colbase * 2048,
                  bvF + colbase, Cv, 2048, 0, true);
    }
}

__global__ __launch_bounds__(256, 2) void oproj_fast(
    const __hip_bfloat16* __restrict__ A, const __hip_bfloat16* __restrict__ Wo,
    const float* __restrict__ boF, float* __restrict__ C) {
    gemm_tile(A + (size_t)blockIdx.y * 128 * 2048,
              Wo + (size_t)blockIdx.x * 128 * 2048, boF + blockIdx.x * 128,
              C + (size_t)blockIdx.y * 128 * 2048 + blockIdx.x * 128, 2048, 2048);
}

// ==================== FALLBACK PATH GEMMs (round-3 style) ===================
template <bool F32>
__global__ __launch_bounds__(256, 2) void qkv_kernel(
    const int* __restrict__ flag, const void* __restrict__ Xv,
    const void* __restrict__ Wqv, const void* __restrict__ Wkv,
    const void* __restrict__ Wvv, const float* __restrict__ bqF,
    const float* __restrict__ bkF, const float* __restrict__ bvF,
    __hip_bfloat16* __restrict__ Qb, __hip_bfloat16* __restrict__ Kb,
    __hip_bfloat16* __restrict__ Vb) {
    if ((*flag == 1) != F32) return;
    using T = typename std::conditional<F32, float, __hip_bfloat16>::type;
    const T* X = (const T*)Xv;
    const int nt = blockIdx.x, mt = blockIdx.y;
    const T* W;
    const float* bias;
    __hip_bfloat16* C;
    int ldc, colbase;
    if (nt < 16)      { W = (const T*)Wqv; bias = bqF; C = Qb; ldc = 2048; colbase = nt * 128; }
    else if (nt < 20) { W = (const T*)Wkv; bias = bkF; C = Kb; ldc = 512;  colbase = (nt - 16) * 128; }
    else              { W = (const T*)Wvv; bias = bvF; C = Vb; ldc = 512;  colbase = (nt - 20) * 128; }
    gemm_tile(X + (size_t)mt * 128 * 2048, W + (size_t)colbase * 2048, bias + colbase,
              C + (size_t)mt * 128 * ldc + colbase, 2048, ldc);
}

template <bool F32>
__global__ __launch_bounds__(256, 2) void oproj_kernel(
    const int* __restrict__ flag, const __hip_bfloat16* __restrict__ A,
    const void* __restrict__ Wov, const float* __restrict__ boF,
    float* __restrict__ C) {
    if ((*flag == 1) != F32) return;
    using T = typename std::conditional<F32, float, __hip_bfloat16>::type;
    gemm_tile(A + (size_t)blockIdx.y * 128 * 2048,
              (const T*)Wov + (size_t)blockIdx.x * 128 * 2048, boF + blockIdx.x * 128,
              C + (size_t)blockIdx.y * 128 * 2048 + blockIdx.x * 128, 2048, 2048);
}

// ---------------------------------------------------------------------------
// Flash attention v5 (R2-proven structure; best measured 92.8-94.7us) at
// (256,5): 5 blocks/CU (LDS 5x32KB = 160KB exactly); R7 run showed attn4
// dropped out of top-5 (<96us) with this setting — kept.
// ---------------------------------------------------------------------------
__global__ __launch_bounds__(256, 5) void attn4_kernel(
    const __hip_bfloat16* __restrict__ Qg, const __hip_bfloat16* __restrict__ Kg,
    const ushort_t* __restrict__ Vt, const float* __restrict__ slopesF,
    __hip_bfloat16* __restrict__ Og) {
    constexpr int S = 2048, WIN = 1024;
    constexpr float LOG2E = 1.44269504f;
    constexpr float SCALE2 = 0.125f * LOG2E;
    constexpr float NEGBIG = -3e38f;
    __shared__ __align__(16) ushort_t K0s[64 * 64];
    __shared__ __align__(16) ushort_t V0s[64 * 64];
    __shared__ __align__(16) ushort_t K1s[64 * 64];
    __shared__ __align__(16) ushort_t V1s[64 * 64];

    // XCD-aware decode: blocks sharing (b,hkv) land on one XCD (p%8 = xcd).
    const int p = blockIdx.x;
    const int xcd = p & 7;
    const int slot = p >> 3;
    const int bh = (slot >> 7) * 8 + xcd;   // b*8 + hkv
    const int h2 = (slot >> 5) & 3;
    const int qt = 31 - (slot & 31);        // long blocks (high qt) first
    const int b = bh >> 3, hkv = bh & 7;
    const int h = hkv * 4 + h2;
    const int i0 = qt * 64;

    const int tid = threadIdx.x;
    const int wave = tid >> 6, lane = tid & 63;
    const int quad = lane >> 4, l15 = lane & 15;
    const int jl = lane >> 3, cc = lane & 7;
    const float slope2 = slopesF[h] * LOG2E;

    const ushort_t* kbase = (const ushort_t*)Kg + (size_t)(b * S) * 512 + hkv * 64;
    const ushort_t* vbase = Vt + ((size_t)bh * 64) * 2048;

    auto stage = [&](int j0, ushort_t* Ks, ushort_t* Vs) {
        const int row0 = wave * 16;
#pragma unroll
        for (int t = 0; t < 2; ++t) {
            const int r = row0 + t * 8 + jl;
            GLD_LDS(kbase + (size_t)(j0 + r) * 512 + ((cc ^ (r & 7)) * 8),
                    Ks + (row0 + t * 8) * 64);
            GLD_LDS(vbase + (size_t)r * 2048 + j0 + ((cc ^ (r & 7)) * 8),
                    Vs + (row0 + t * 8) * 64);
        }
    };

    // Q fragments: lane holds Q[row=i][dh=kk*32+quad*8+..] -> B-operand of K·Q^T
    const int i = i0 + wave * 16 + l15;  // this lane's q-row
    const __hip_bfloat16* qbase = Qg + ((size_t)(b * S + i)) * 2048 + h * 64;
    bf16x8 aq0 = *(const bf16x8*)(qbase + quad * 8);
    bf16x8 aq1 = *(const bf16x8*)(qbase + 32 + quad * 8);

    union { ushort4 u; bf16x4 v; } onesu;
    onesu.u = make_ushort4(0x3F80, 0x3F80, 0x3F80, 0x3F80);  // bf16 1.0 x4
    const bf16x4 onesf = onesu.v;

    f32x4 oaccT[4];  // O^T: lane holds q=i, dh = ni*16 + quad*4 + r
#pragma unroll
    for (int ni = 0; ni < 4; ++ni) oaccT[ni] = {0.f, 0.f, 0.f, 0.f};
    f32x4 lacc = {0.f, 0.f, 0.f, 0.f};  // lacc[0] = running sum of P for this q
    float m_i = -1e30f;

    auto compute = [&](int j0, const ushort_t* Ks, const ushort_t* Vs, bool masked) {
        // ---- S^T = K·Q^T : D[j=ni*16+quad*4+r][q=l15] ----
        f32x4 st[4];
#pragma unroll
        for (int ni = 0; ni < 4; ++ni) st[ni] = {0.f, 0.f, 0.f, 0.f};
#pragma unroll
        for (int kk = 0; kk < 2; ++kk) {
            const bf16x8 aqk = kk ? aq1 : aq0;
#pragma unroll
            for (int ni = 0; ni < 4; ++ni) {
                const int row = ni * 16 + l15;
                bf16x8 kf = *(const bf16x8*)(Ks + row * 64 + ((kk * 4 + quad) ^ (row & 7)) * 8);
                st[ni] = MFMA_BF16(kf, aqk, st[ni]);
            }
        }
        // ---- scores: all 16 j-values belong to THIS lane's q-row ----
        float sv[4][4];
#pragma unroll
        for (int ni = 0; ni < 4; ++ni)
#pragma unroll
            for (int r = 0; r < 4; ++r) {
                const int rel = (j0 + ni * 16 + quad * 4 + r) - i;
                sv[ni][r] = fmaf(st[ni][r], SCALE2, slope2 * (float)rel);
            }
        if (masked) {
#pragma unroll
            for (int ni = 0; ni < 4; ++ni)
#pragma unroll
                for (int r = 0; r < 4; ++r) {
                    const int rel = (j0 + ni * 16 + quad * 4 + r) - i;
                    if (!((unsigned)(-rel) < (unsigned)WIN)) sv[ni][r] = NEGBIG;
                }
        }
        // ---- row max: max3-shaped tree, then 2 cross-quad shuffles ----
        float mx = fmax3(fmax3(sv[0][0], sv[0][1], sv[0][2]),
                         fmax3(sv[0][3], sv[1][0], sv[1][1]),
                         fmax3(sv[1][2], sv[1][3], sv[2][0]));
        float my = fmax3(fmax3(sv[2][1], sv[2][2], sv[2][3]),
                         fmax3(sv[3][0], sv[3][1], sv[3][2]), sv[3][3]);
        mx = fmaxf(mx, my);
        mx = fmaxf(mx, __shfl_xor(mx, 16));
        mx = fmaxf(mx, __shfl_xor(mx, 32));
        // ---- defer-max: rescale only when the running max grew by > 8 ----
        if (!__all(mx <= m_i + 8.f)) {
            const float mn = fmaxf(m_i, mx);
            const float alpha = exp2f(m_i - mn);
            m_i = mn;
#pragma unroll
            for (int ni = 0; ni < 4; ++ni)
#pragma unroll
                for (int r = 0; r < 4; ++r) oaccT[ni][r] *= alpha;
            lacc[0] *= alpha;
        }
        float pv[4][4];
#pragma unroll
        for (int ni = 0; ni < 4; ++ni)
#pragma unroll
            for (int r = 0; r < 4; ++r) pv[ni][r] = exp2f(sv[ni][r] - m_i);
        // P fragments: B[k=quad*4+r][n=l15] for j-chunk c == register frag c. No LDS!
        bf16x4 pf[4];
#pragma unroll
        for (int c = 0; c < 4; ++c) pf[c] = pack4(pv[c][0], pv[c][1], pv[c][2], pv[c][3]);
        // row-sum via MFMA: D[m][q] = sum_k P[k][q] for every m -> lacc[0]
#pragma unroll
        for (int c = 0; c < 4; ++c) lacc = MFMA16(onesf, pf[c], lacc);
        // ---- O^T += V^T · P : A = V^T[dh=ni*16+l15][j=c*16+quad*4+..] (b64) ----
#pragma unroll
        for (int ni = 0; ni < 4; ++ni) {
            const int row = ni * 16 + l15;
#pragma unroll
            for (int c = 0; c < 4; ++c) {
                const int cj = c * 2 + (quad >> 1);
                bf16x4 vf = *(const bf16x4*)(Vs + row * 64 + ((cj ^ (row & 7)) * 8) +
                                             (quad & 1) * 4);
                oaccT[ni] = MFMA16(vf, pf[c], oaccT[ni]);
            }
        }
    };

    const int jt_lo = (i0 - WIN + 1) > 0 ? ((i0 - WIN + 1) >> 6) : 0;
    int jt = jt_lo;
    stage(jt * 64, K0s, V0s);
    for (;;) {
        __syncthreads();
        if (jt < qt) stage((jt + 1) * 64, K1s, V1s);
        compute(jt * 64, K0s, V0s, (jt == qt) || (qt - jt >= 16));
        if (++jt > qt) break;
        __syncthreads();
        if (jt < qt) stage((jt + 1) * 64, K0s, V0s);
        compute(jt * 64, K1s, V1s, (jt == qt) || (qt - jt >= 16));
        if (++jt > qt) break;
    }
    // epilogue: lane holds q=i; dh = ni*16+quad*4+r (consecutive r -> 8B stores)
    const float inv = 1.0f / lacc[0];
    __hip_bfloat16* obase = Og + ((size_t)(b * S + i)) * 2048 + h * 64;
#pragma unroll
    for (int ni = 0; ni < 4; ++ni) {
        ushort4 o4 = make_ushort4(f2bfbits(oaccT[ni][0] * inv), f2bfbits(oaccT[ni][1] * inv),
                                  f2bfbits(oaccT[ni][2] * inv), f2bfbits(oaccT[ni][3] * inv));
        *(ushort4*)((ushort_t*)obase + ni * 16 + quad * 4) = o4;
    }
}

// ---------------------------------------------------------------------------
// Fallback attention (round-3 proven; used when ws too small for fast path).
// ---------------------------------------------------------------------------
__global__ __launch_bounds__(256, 2) void attn_kernel(
    const __hip_bfloat16* __restrict__ Qg, const __hip_bfloat16* __restrict__ Kg,
    const __hip_bfloat16* __restrict__ Vg, const float* __restrict__ slopesF,
    __hip_bfloat16* __restrict__ Og) {
    constexpr int S = 2048, WIN = 1024;
    constexpr float SCALE = 0.125f;
    constexpr float LOG2E = 1.44269504f;
    __shared__ __align__(16) ushort_t P_lds[64 * 72];
    __shared__ __align__(16) ushort_t Vts[64 * 72];

    const int tile = blockIdx.x;
    const int qt = tile & 31;
    const int h = (tile >> 5) & 31;
    const int b = tile >> 10;
    const int i0 = qt * 64;
    const int hkv = h >> 2;
    const int tid = threadIdx.x;
    const int wave = tid >> 6, lane = tid & 63;
    const int quad = lane >> 4, l15 = lane & 15;
    const float slope = slopesF[h];

    const int qrow = i0 + wave * 16 + l15;
    const __hip_bfloat16* qbase = Qg + ((size_t)(b * S + qrow)) * 2048 + h * 64;
    bf16x8 aq[2];
    aq[0] = *(const bf16x8*)(qbase + quad * 8);
    aq[1] = *(const bf16x8*)(qbase + 32 + quad * 8);

    f32x4 oacc[4];
#pragma unroll
    for (int ni = 0; ni < 4; ++ni) oacc[ni] = {0.f, 0.f, 0.f, 0.f};
    float m_i[4], l_i[4];
#pragma unroll
    for (int r = 0; r < 4; ++r) { m_i[r] = -1e30f; l_i[r] = 0.f; }

    const int jt_lo = (i0 - WIN + 1) > 0 ? ((i0 - WIN + 1) >> 6) : 0;
    for (int jt = jt_lo; jt <= qt; ++jt) {
        const int j0 = jt * 64;
#pragma unroll
        for (int it = 0; it < 2; ++it) {
            const int j = it * 32 + (tid >> 3);
            const int dh0 = (tid & 7) * 8;
            u16x8 vv = *(const u16x8*)(Vg + ((size_t)(b * S + j0 + j)) * 512 + hkv * 64 + dh0);
#pragma unroll
            for (int e = 0; e < 8; ++e) Vts[(dh0 + e) * 72 + j] = vv[e];
        }
        f32x4 sacc[4];
#pragma unroll
        for (int ni = 0; ni < 4; ++ni) sacc[ni] = {0.f, 0.f, 0.f, 0.f};
#pragma unroll
        for (int kk = 0; kk < 2; ++kk) {
#pragma unroll
            for (int ni = 0; ni < 4; ++ni) {
                bf16x8 bkf = *(const bf16x8*)(Kg + ((size_t)(b * S + j0 + ni * 16 + l15)) * 512 +
                                              hkv * 64 + kk * 32 + quad * 8);
                sacc[ni] = MFMA_BF16(aq[kk], bkf, sacc[ni]);
            }
        }
#pragma unroll
        for (int r = 0; r < 4; ++r) {
            const int i = i0 + wave * 16 + quad * 4 + r;
            float sv[4];
            float rowmax = -1e30f;
#pragma unroll
            for (int ni = 0; ni < 4; ++ni) {
                const int j = j0 + ni * 16 + l15;
                float s = sacc[ni][r] * SCALE + slope * (float)(j - i);
                const bool valid = (j <= i) && ((i - j) < WIN);
                s = valid ? s : -1e30f;
                sv[ni] = s;
                rowmax = fmaxf(rowmax, s);
            }
#pragma unroll
            for (int off = 1; off < 16; off <<= 1)
                rowmax = fmaxf(rowmax, __shfl_xor(rowmax, off));
            const float mn = fmaxf(m_i[r], rowmax);
            const float alpha = exp2f((m_i[r] - mn) * LOG2E);
            float rowsum = 0.f;
#pragma unroll
            for (int ni = 0; ni < 4; ++ni) {
                const float p = (sv[ni] > -1e29f) ? exp2f((sv[ni] - mn) * LOG2E) : 0.f;
                P_lds[(wave * 16 + quad * 4 + r) * 72 + ni * 16 + l15] = f2bfbits(p);
                rowsum += p;
            }
#pragma unroll
            for (int off = 1; off < 16; off <<= 1) rowsum += __shfl_xor(rowsum, off);
            l_i[r] = l_i[r] * alpha + rowsum;
            m_i[r] = mn;
#pragma unroll
            for (int ni = 0; ni < 4; ++ni) oacc[ni][r] *= alpha;
        }
        __syncthreads();
#pragma unroll
        for (int kk = 0; kk < 2; ++kk) {
            bf16x8 ap = *(const bf16x8*)(P_lds + (wave * 16 + l15) * 72 + kk * 32 + quad * 8);
#pragma unroll
            for (int ni = 0; ni < 4; ++ni) {
                bf16x8 bvf = *(const bf16x8*)(Vts + (ni * 16 + l15) * 72 + kk * 32 + quad * 8);
                oacc[ni] = MFMA_BF16(ap, bvf, oacc[ni]);
            }
        }
        __syncthreads();
    }
#pragma unroll
    for (int ni = 0; ni < 4; ++ni) {
#pragma unroll
        for (int r = 0; r < 4; ++r) {
            const int srow = i0 + wave * 16 + quad * 4 + r;
            const float v = oacc[ni][r] / l_i[r];
            Og[((size_t)(b * S + srow)) * 2048 + h * 64 + ni * 16 + l15] = __float2bfloat16(v);
        }
    }
}

extern "C" void kernel_launch(void* const* d_in, const int* in_sizes, int n_in,
                              void* d_out, int out_size, void* d_ws, size_t ws_size,
                              hipStream_t stream) {
    (void)in_sizes; (void)n_in; (void)out_size;
    const void* X  = d_in[0];
    const void* Wq = d_in[1];
    const void* bq = d_in[2];
    const void* Wk = d_in[3];
    const void* bk = d_in[4];
    const void* Wv = d_in[5];
    const void* bv = d_in[6];
    const void* Wo = d_in[7];
    const void* bo = d_in[8];
    const void* sl = d_in[9];
    float* outp = (float*)d_out;

    char* ws = (char*)d_ws;
    const size_t SZ_X  = (size_t)4096 * 2048 * 2;
    const size_t SZ_WQ = (size_t)2048 * 2048 * 2;
    const size_t SZ_WK = (size_t)512 * 2048 * 2;
    const size_t SZ_Q  = SZ_X;
    const size_t SZ_K  = (size_t)4096 * 512 * 2;
    const size_t FAST_NEED  = SZ_X + SZ_WQ + 2 * SZ_WK + SZ_Q + 2 * SZ_K + 65536;
    const size_t FAST_NEED2 = FAST_NEED + SZ_WQ;  // + separate Wob

    if (ws_size >= FAST_NEED) {
        size_t o = 0;
        __hip_bfloat16* Xb  = (__hip_bfloat16*)(ws + o); o += SZ_X;
        __hip_bfloat16* Wqb = (__hip_bfloat16*)(ws + o); o += SZ_WQ;
        __hip_bfloat16* Wkb = (__hip_bfloat16*)(ws + o); o += SZ_WK;
        __hip_bfloat16* Wvb = (__hip_bfloat16*)(ws + o); o += SZ_WK;
        __hip_bfloat16* Qb  = (__hip_bfloat16*)(ws + o); o += SZ_Q;
        __hip_bfloat16* Kb  = (__hip_bfloat16*)(ws + o); o += SZ_K;
        ushort_t*       Vtg = (ushort_t*)(ws + o);       o += SZ_K;  // Vt lives in Vb slot
        __hip_bfloat16* Ab  = Xb;             // X dead after qkv_fast
        int*   flag    = (int*)(ws + o);
        float* slopesF = (float*)(ws + o + 1024);
        float* bqF     = (float*)(ws + o + 4096);
        float* bkF     = bqF + 2048;
        float* bvF     = bkF + 512;
        float* boF     = bvF + 512;

        if (ws_size >= FAST_NEED2) {
            // ---- tier-2: 4-kernel pipeline, separate Wob ----
            __hip_bfloat16* Wob = (__hip_bfloat16*)(ws + o + 65536);
            cvt5_kernel<<<2048, 256, 0, stream>>>(
                X, Wq, Wk, Wv, Wo, bq, bk, bv, bo, sl, (ushort_t*)Xb, (ushort_t*)Wqb,
                (ushort_t*)Wkb, (ushort_t*)Wvb, (ushort_t*)Wob, slopesF, bqF, bkF, bvF,
                boF);
            qkv_fast<<<dim3(24, 32), 256, 0, stream>>>(Xb, Wqb, Wkb, Wvb, bqF, bkF, bvF,
                                                       Qb, Kb, Vtg);
            attn4_kernel<<<dim3(2048), 256, 0, stream>>>(Qb, Kb, Vtg, slopesF, Ab);
            oproj_fast<<<dim3(16, 32), 256, 0, stream>>>(Ab, Wob, boF, outp);
        } else {
            // ---- tier-1: Wob aliases Wqb (cvt after qkv) ----
            __hip_bfloat16* Wob = Wqb;
            detect_kernel<<<1, 256, 0, stream>>>((const ushort_t*)X, bq, bk, bv, bo, sl,
                                                 flag, slopesF, bqF, bkF, bvF, boF);
            cvt4_kernel<<<2048, 256, 0, stream>>>(flag, X, Wq, Wk, Wv, (ushort_t*)Xb,
                                                  (ushort_t*)Wqb, (ushort_t*)Wkb,
                                                  (ushort_t*)Wvb);
            qkv_fast<<<dim3(24, 32), 256, 0, stream>>>(Xb, Wqb, Wkb, Wvb, bqF, bkF, bvF,
                                                       Qb, Kb, Vtg);
            cvt_kernel<<<2048, 256, 0, stream>>>(flag, Wo, (ushort_t*)Wob, 2048 * 2048 / 4);
            attn4_kernel<<<dim3(2048), 256, 0, stream>>>(Qb, Kb, Vtg, slopesF, Ab);
            oproj_fast<<<dim3(16, 32), 256, 0, stream>>>(Ab, Wob, boF, outp);
        }
    } else {
        const size_t MB = 1024 * 1024;
        __hip_bfloat16* Qb = (__hip_bfloat16*)(ws);
        __hip_bfloat16* Kb = (__hip_bfloat16*)(ws + 16 * MB);
        __hip_bfloat16* Vb = (__hip_bfloat16*)(ws + 20 * MB);
        __hip_bfloat16* Ab = (__hip_bfloat16*)(ws + 24 * MB);
        int*   flag    = (int*)(ws + 40 * MB);
        float* slopesF = (float*)(ws + 40 * MB + 1024);
        float* bqF     = (float*)(ws + 40 * MB + 4096);
        float* bkF     = bqF + 2048;
        float* bvF     = bkF + 512;
        float* boF     = bvF + 512;

        detect_kernel<<<1, 256, 0, stream>>>((const ushort_t*)X, bq, bk, bv, bo, sl,
                                             flag, slopesF, bqF, bkF, bvF, boF);
        qkv_kernel<false><<<dim3(24, 32), 256, 0, stream>>>(flag, X, Wq, Wk, Wv,
                                                            bqF, bkF, bvF, Qb, Kb, Vb);
        qkv_kernel<true><<<dim3(24, 32), 256, 0, stream>>>(flag, X, Wq, Wk, Wv,
                                                           bqF, bkF, bvF, Qb, Kb, Vb);
        attn_kernel<<<dim3(2048), 256, 0, stream>>>(Qb, Kb, Vb, slopesF, Ab);
        oproj_kernel<false><<<dim3(16, 32), 256, 0, stream>>>(flag, Ab, Wo, boF, outp);
        oproj_kernel<true><<<dim3(16, 32), 256, 0, stream>>>(flag, Ab, Wo, boF, outp);
    }
}